// Round 16
// baseline (3402.214 us; speedup 1.0000x reference)
//
#include <hip/hip_runtime.h>

#define B_ 2
#define N_ 16384
#define K_ 2048
#define CBEV 256
#define HH 128
#define WW 128
#define CIN 288
#define COUT 128

typedef float f32x2 __attribute__((ext_vector_type(2)));
typedef float f32x4 __attribute__((ext_vector_type(4)));

// DPP max step: cross-lane move at VALU latency; bound_ctrl=1 fills invalid
// lanes with 0 -- safe identity since all reduced values are >= 0.
template <int CTRL>
__device__ __forceinline__ float dpp_max(float v) {
  int x = __builtin_amdgcn_update_dpp(0, __float_as_int(v), CTRL, 0xf, 0xf, true);
  return fmaxf(v, __int_as_float(x));
}

// ---------------- spatial sort (band-serpentine 32x32 over x,y) ----------------
// Continuous curve: any run of consecutive cells is spatially compact, so
// every wave gets a small bbox (no Morton discontinuities).
__global__ __launch_bounds__(1024) void sort_kernel(
    const float4* __restrict__ points, float4* __restrict__ sorted)
{
  const int b = blockIdx.x, t = threadIdx.x, lane = t & 63, wid = t >> 6;
  const float4* pts = points + (size_t)b * N_;
  float4* dst = sorted + (size_t)b * N_;
  __shared__ int hist[1024];
  __shared__ int wsum[16];
  hist[t] = 0;
  __syncthreads();
  int cells[16];
#pragma unroll
  for (int j = 0; j < 16; ++j) {
    float4 p = pts[t * 16 + j];
    int cx = min(max((int)((p.x + 51.2f) * 0.3125f), 0), 31);
    int cy = min(max((int)((p.y + 51.2f) * 0.3125f), 0), 31);
    int band = cy >> 2;                       // 0..7 (4 rows each)
    int rib = cy & 3;                         // row in band
    int col = (band & 1) ? (31 - cx) : cx;    // serpentine join at band ends
    int c = band * 128 + col * 4 + rib;       // 0..1023, continuous curve
    cells[j] = c;
    atomicAdd(&hist[c], 1);
  }
  __syncthreads();
  int own = hist[t];
  int v = own;
#pragma unroll
  for (int off = 1; off < 64; off <<= 1) {
    int n = __shfl_up(v, off);
    if (lane >= off) v += n;
  }
  if (lane == 63) wsum[wid] = v;
  __syncthreads();
  int base = 0;
  for (int i = 0; i < wid; ++i) base += wsum[i];
  int excl = base + v - own;
  __syncthreads();
  hist[t] = excl;
  __syncthreads();
#pragma unroll
  for (int j = 0; j < 16; ++j) {
    float4 p = pts[t * 16 + j];
    int pos = atomicAdd(&hist[cells[j]], 1);
    dst[pos] = p;
  }
}

// ---------------- FPS: 8 waves, wave-level bbox prune ----------------
// Skeleton cost (barrier + post-release issue burst + SIMD time-slicing)
// scales with wave count: R11-R15 pinned at ~2200us with 16 waves regardless
// of dense-work cuts. 8 waves halves the skeleton; serpentine keeps active
// waves at ~1-2 (wave = one 102x13m band).
#define FPS_T 512
#define FPS_PPT 32
#define FPS_PAIRS 16
#define REG_PAIRS 4  // pairs 0..3 x,y in VGPRs; pairs 4..15 in LDS f32x4

__global__ __launch_bounds__(FPS_T)
__attribute__((amdgpu_waves_per_eu(2, 2))) void fps_kernel(
    const float4* __restrict__ points, const float4* __restrict__ sorted,
    float4* __restrict__ keypts)
{
  const int b = blockIdx.x, t = threadIdx.x, lane = t & 63, wid = t >> 6;
  const float4* sp = sorted + (size_t)b * N_;

  __shared__ f32x4 xyq[FPS_PAIRS - REG_PAIRS][FPS_T];  // 96KB (x0,x1,y0,y1)
  __shared__ float4 scoord[2][8];                      // (x,y,z,val) per wave
  __shared__ float4 kpbuf[K_];                         // 32KB keypoint buffer

  const int base = t * FPS_PPT;

  f32x2 rx[REG_PAIRS], ry[REG_PAIRS];  // 16 VGPRs, statically indexed
  f32x2 zz[FPS_PAIRS], dd[FPS_PAIRS];  // 64 VGPRs
  float bxmin = 1e30f, bxmax = -1e30f, bymin = 1e30f, bymax = -1e30f;
  float bzmin = 1e30f, bzmax = -1e30f;
#pragma unroll
  for (int j = 0; j < FPS_PAIRS; ++j) {
    float4 p0 = sp[base + 2 * j];
    float4 p1 = sp[base + 2 * j + 1];
    if (j < REG_PAIRS) {
      rx[j].x = p0.x; rx[j].y = p1.x;
      ry[j].x = p0.y; ry[j].y = p1.y;
    } else {
      f32x4 v4; v4.x = p0.x; v4.y = p1.x; v4.z = p0.y; v4.w = p1.y;
      xyq[j - REG_PAIRS][t] = v4;
    }
    zz[j].x = p0.z; zz[j].y = p1.z;
    dd[j].x = 1e10f; dd[j].y = 1e10f;
    bxmin = fminf(bxmin, fminf(p0.x, p1.x)); bxmax = fmaxf(bxmax, fmaxf(p0.x, p1.x));
    bymin = fminf(bymin, fminf(p0.y, p1.y)); bymax = fmaxf(bymax, fmaxf(p0.y, p1.y));
    bzmin = fminf(bzmin, fminf(p0.z, p1.z)); bzmax = fmaxf(bzmax, fmaxf(p0.z, p1.z));
  }
  // WAVE-level bbox: one skip decision per wave
#pragma unroll
  for (int off = 1; off < 64; off <<= 1) {
    bxmin = fminf(bxmin, __shfl_xor(bxmin, off));
    bxmax = fmaxf(bxmax, __shfl_xor(bxmax, off));
    bymin = fminf(bymin, __shfl_xor(bymin, off));
    bymax = fmaxf(bymax, __shfl_xor(bymax, off));
    bzmin = fminf(bzmin, __shfl_xor(bzmin, off));
    bzmax = fmaxf(bzmax, __shfl_xor(bzmax, off));
  }
  float wtmax = 1e10f;  // this wave's exact max dd (== published wv)

  float4 q = points[(size_t)b * N_];  // seed = original index 0
  if (t == 0) kpbuf[0] = make_float4(q.x, q.y, q.z, q.w);

  for (int it = 1; it < K_; ++it) {
    const int pr = it & 1;
    // conservative lower bound of dist^2 from q to the WAVE bbox (uniform)
    float dxl = fmaxf(fmaxf(bxmin - q.x, q.x - bxmax), 0.f);
    float dyl = fmaxf(fmaxf(bymin - q.y, q.y - bymax), 0.f);
    float dzl = fmaxf(fmaxf(bzmin - q.z, q.z - bzmax), 0.f);
    float lb = dxl * dxl + dyl * dyl + dzl * dzl;
    // margin covers <=9ulp RN error; lb>=wtmax>=dd[j] forall j -> exact no-op
    if (lb * 0.999999f < wtmax) {
#pragma clang fp contract(off)
      f32x2 qx, qy, qz;
      qx.x = q.x; qx.y = q.x;
      qy.x = q.y; qy.y = q.y;
      qz.x = q.z; qz.y = q.z;
      f32x2 rm; rm.x = -1.f; rm.y = -1.f;
      // reg-resident pairs: pure VALU
#pragma unroll
      for (int j = 0; j < REG_PAIRS; ++j) {
        // EXACT reference arithmetic: RN sub/mul/add, ((dx^2+dy^2)+dz^2)
        f32x2 dx = rx[j] - qx;
        f32x2 dy = ry[j] - qy;
        f32x2 dz = zz[j] - qz;
        f32x2 d = dx * dx + dy * dy + dz * dz;
        d = __builtin_elementwise_min(dd[j], d);
        dd[j] = d;
        rm = __builtin_elementwise_max(rm, d);
      }
      // LDS pairs: one ds_read_b128 each
#pragma unroll
      for (int j = REG_PAIRS; j < FPS_PAIRS; ++j) {
        f32x4 v4 = xyq[j - REG_PAIRS][t];
        f32x2 x; x.x = v4.x; x.y = v4.y;
        f32x2 y; y.x = v4.z; y.y = v4.w;
        f32x2 dx = x - qx;
        f32x2 dy = y - qy;
        f32x2 dz = zz[j] - qz;
        f32x2 d = dx * dx + dy * dy + dz * dz;
        d = __builtin_elementwise_min(dd[j], d);
        dd[j] = d;
        rm = __builtin_elementwise_max(rm, d);
      }
      float tmax = fmaxf(rm.x, rm.y);
      // wave max via DPP
      float wred = tmax;
      wred = dpp_max<0x111>(wred);  // row_shr:1
      wred = dpp_max<0x112>(wred);  // row_shr:2
      wred = dpp_max<0x114>(wred);  // row_shr:4
      wred = dpp_max<0x118>(wred);  // row_shr:8
      wred = dpp_max<0x142>(wred);  // row_bcast:15
      wred = dpp_max<0x143>(wred);  // row_bcast:31
      float wv = __int_as_float(
          __builtin_amdgcn_readlane(__float_as_int(wred), 63));
      wtmax = wv;  // stays exact while pruned (dd unchanged then)
      // winner lane = lowest tied lane (lanes are sorted-index-ordered)
      unsigned long long mb = __ballot(tmax == wv);
      int src = __ffsll((long long)mb) - 1;
      if (lane == src) {
        // rescan own dd; reverse order + x-after-y -> smallest offset wins
        int tjoff = 0;
#pragma unroll
        for (int jj = FPS_PAIRS - 1; jj >= 0; --jj) {
          if (dd[jj].y == wv) tjoff = 2 * jj + 1;
          if (dd[jj].x == wv) tjoff = 2 * jj;
        }
        float xx = 0.f, yy = 0.f;
#pragma unroll
        for (int jj = 0; jj < REG_PAIRS; ++jj) {  // static indexing only
          xx = (tjoff == 2 * jj) ? rx[jj].x : xx;
          xx = (tjoff == 2 * jj + 1) ? rx[jj].y : xx;
          yy = (tjoff == 2 * jj) ? ry[jj].x : yy;
          yy = (tjoff == 2 * jj + 1) ? ry[jj].y : yy;
        }
        if (tjoff >= 2 * REG_PAIRS) {  // dynamic LDS fetch is fine
          const float* lp = (const float*)&xyq[(tjoff >> 1) - REG_PAIRS][t];
          int sub = tjoff & 1;
          xx = lp[sub];
          yy = lp[2 + sub];
        }
        float zs = 0.f;
#pragma unroll
        for (int jj = 0; jj < FPS_PAIRS; ++jj) {
          zs = (tjoff == 2 * jj) ? zz[jj].x : zs;
          zs = (tjoff == 2 * jj + 1) ? zz[jj].y : zs;
        }
        scoord[pr][wid] = make_float4(xx, yy, zs, wv);
      }
    } else {
      // pruned wave: winner unchanged; copy last slot to this parity
      if (lane == 0) scoord[pr][wid] = scoord[pr ^ 1][wid];
    }
    __syncthreads();  // single barrier; parity double-buffer avoids WAR
    // global winner among 8 slots: one b128 read + 3 DPP + readlane bcast
    float4 f4 = scoord[pr][lane & 7];
    float v = f4.w;
    float g = v;
    g = dpp_max<0x111>(g);
    g = dpp_max<0x112>(g);
    g = dpp_max<0x114>(g);
    float gm = __int_as_float(
        __builtin_amdgcn_readlane(__float_as_int(g), 7));
    unsigned long long mb2 = __ballot(v == gm);
    int sww = (__ffsll((long long)mb2) - 1) & 7;  // uniform (from SGPR mask)
    q.x = __int_as_float(__builtin_amdgcn_readlane(__float_as_int(f4.x), sww));
    q.y = __int_as_float(__builtin_amdgcn_readlane(__float_as_int(f4.y), sww));
    q.z = __int_as_float(__builtin_amdgcn_readlane(__float_as_int(f4.z), sww));
    if (t == 0) kpbuf[it] = make_float4(q.x, q.y, q.z, 0.f);  // LDS only
  }
  __syncthreads();
  // single coalesced burst of all keypoints at the end
  for (int i = t; i < K_; i += FPS_T)
    keypts[(size_t)b * K_ + i] = kpbuf[i];
}

// ---------------- bilinear BEV sampling ----------------
__global__ __launch_bounds__(256) void bilinear_kernel(
    const float* __restrict__ bev, const float4* __restrict__ keypts,
    float* __restrict__ feat)
{
  const int kb = blockIdx.x;      // 0..B*K-1
  const int b = kb >> 11;         // / K_
  const int c = threadIdx.x;      // channel
  float4 kp = keypts[kb];
  // exact reference op order: (x - (-51.2)) / 0.1 / 8.0 in f32 RN
  float x = __fsub_rn(kp.x, -51.2f); x = x / 0.1f; x = x / 8.0f;
  float y = __fsub_rn(kp.y, -51.2f); y = y / 0.1f; y = y / 8.0f;
  int xf = (int)floorf(x);
  int yf = (int)floorf(y);
  int x0 = min(max(xf, 0), WW - 1);
  int x1 = min(max(xf + 1, 0), WW - 1);
  int y0 = min(max(yf, 0), HH - 1);
  int y1 = min(max(yf + 1, 0), HH - 1);
  float x0f = (float)x0, x1f = (float)x1, y0f = (float)y0, y1f = (float)y1;
  float wa = (x1f - x) * (y1f - y);
  float wb = (x1f - x) * (y - y0f);
  float wc = (x - x0f) * (y1f - y);
  float wd = (x - x0f) * (y - y0f);
  const float* bb = bev + ((size_t)b * CBEV + c) * (HH * WW);
  float Ia = bb[y0 * WW + x0];
  float Ib = bb[y1 * WW + x0];
  float Ic = bb[y0 * WW + x1];
  float Id = bb[y1 * WW + x1];
  float v = Ia * wa + Ib * wb + Ic * wc + Id * wd;
  feat[(size_t)kb * CIN + c] = v;
}

// ---------------- grouping + 2x tiny MLP + maxpool ----------------
__global__ __launch_bounds__(256) void group_kernel(
    const float4* __restrict__ points, const float4* __restrict__ keypts,
    const float* __restrict__ sa_w1, const float* __restrict__ sa_s1,
    const float* __restrict__ sa_b1, const float* __restrict__ sa_w2,
    const float* __restrict__ sa_s2, const float* __restrict__ sa_b2,
    float* __restrict__ feat)
{
  const int w = threadIdx.x >> 6;      // wave id 0..3
  const int lane = threadIdx.x & 63;
  const int kb = blockIdx.x * 4 + w;   // keypoint id
  const int b = kb >> 11;
  const int d = lane & 15;
  __shared__ int l1[4][16];
  __shared__ int l2[4][32];
  const float4* pts = points + (size_t)b * N_;
  float4 kp = keypts[kb];
  const float r2a = (float)(0.4 * 0.4);
  const float r2b = (float)(0.8 * 0.8);
  int c1 = 0, c2 = 0;
  for (int base = 0; base < N_; base += 64) {
    float4 p = pts[base + lane];
    float dx = __fsub_rn(kp.x, p.x);
    float dy = __fsub_rn(kp.y, p.y);
    float dz = __fsub_rn(kp.z, p.z);
    float d2 = __fadd_rn(__fadd_rn(__fmul_rn(dx, dx), __fmul_rn(dy, dy)),
                         __fmul_rn(dz, dz));
    unsigned long long m2 = __ballot(d2 < r2b);
    unsigned long long m1 = __ballot(d2 < r2a);
    unsigned long long below = (lane == 0) ? 0ull : ((~0ull) >> (64 - lane));
    if (c2 < 32 && m2) {
      int pos = c2 + __popcll(m2 & below);
      if (((m2 >> lane) & 1ull) && pos < 32) l2[w][pos] = base + lane;
      c2 += __popcll(m2); if (c2 > 32) c2 = 32;
    }
    if (c1 < 16 && m1) {
      int pos = c1 + __popcll(m1 & below);
      if (((m1 >> lane) & 1ull) && pos < 16) l1[w][pos] = base + lane;
      c1 += __popcll(m1); if (c1 > 16) c1 = 16;
    }
    if (c1 >= 16 && c2 >= 32) break;
  }
  __syncthreads();

  float pooled[2];
#pragma unroll
  for (int br = 0; br < 2; ++br) {
    const int wo1 = br * 64, so1 = br * 16, wo2 = br * 256;
    float w1r[4], w2r[16];
#pragma unroll
    for (int c = 0; c < 4; ++c) w1r[c] = sa_w1[wo1 + c * 16 + d];
#pragma unroll
    for (int c = 0; c < 16; ++c) w2r[c] = sa_w2[wo2 + c * 16 + d];
    float s1d = sa_s1[so1 + d], b1d = sa_b1[so1 + d];
    float s2d = sa_s2[so1 + d], b2d = sa_b2[so1 + d];
    int cnt = (br == 0) ? c1 : c2;
    float vm = -1e30f;
    int n = cnt > 0 ? cnt : 1;
    for (int j = 0; j < n; ++j) {
      float g0 = 0.f, g1 = 0.f, g2 = 0.f, g3 = 0.f;
      if (j < cnt) {
        int pi = (br == 0) ? l1[w][j] : l2[w][j];
        float4 p = pts[pi];
        g0 = p.x - kp.x; g1 = p.y - kp.y; g2 = p.z - kp.z; g3 = p.w;
      }
      float a = g0 * w1r[0] + g1 * w1r[1] + g2 * w1r[2] + g3 * w1r[3];
      float h1 = fmaxf(0.f, fmaf(a, s1d, b1d));
      float a2 = 0.f;
#pragma unroll
      for (int c = 0; c < 16; ++c) a2 = fmaf(__shfl(h1, c), w2r[c], a2);
      float h2 = fmaxf(0.f, fmaf(a2, s2d, b2d));
      vm = fmaxf(vm, h2);
    }
    pooled[br] = vm;
  }
  if (lane < 16) {
    feat[(size_t)kb * CIN + 256 + d] = pooled[0];
    feat[(size_t)kb * CIN + 272 + d] = pooled[1];
  }
}

// ---------------- fused linear + relu ----------------
__global__ __launch_bounds__(128) void fuse_kernel(
    const float* __restrict__ feat, const float* __restrict__ fw,
    const float* __restrict__ fs, const float* __restrict__ fb,
    float* __restrict__ out)
{
  __shared__ float rows[8 * CIN];
  const int d = threadIdx.x;
  const size_t r0 = (size_t)blockIdx.x * 8;
  for (int i = d; i < 8 * CIN; i += 128) rows[i] = feat[r0 * CIN + i];
  __syncthreads();
  float acc[8];
#pragma unroll
  for (int r = 0; r < 8; ++r) acc[r] = 0.f;
  for (int c = 0; c < CIN; ++c) {
    float wv = fw[c * COUT + d];
#pragma unroll
    for (int r = 0; r < 8; ++r) acc[r] = fmaf(rows[r * CIN + c], wv, acc[r]);
  }
  float sd = fs[d], bd = fb[d];
#pragma unroll
  for (int r = 0; r < 8; ++r)
    out[(r0 + r) * COUT + d] = fmaxf(0.f, fmaf(acc[r], sd, bd));
}

extern "C" void kernel_launch(void* const* d_in, const int* in_sizes, int n_in,
                              void* d_out, int out_size, void* d_ws, size_t ws_size,
                              hipStream_t stream) {
  const float4* points = (const float4*)d_in[0];
  const float* bev    = (const float*)d_in[1];
  const float* sa_w1  = (const float*)d_in[2];
  const float* sa_s1  = (const float*)d_in[3];
  const float* sa_b1  = (const float*)d_in[4];
  const float* sa_w2  = (const float*)d_in[5];
  const float* sa_s2  = (const float*)d_in[6];
  const float* sa_b2  = (const float*)d_in[7];
  const float* fuse_w = (const float*)d_in[8];
  const float* fuse_s = (const float*)d_in[9];
  const float* fuse_b = (const float*)d_in[10];
  float* out = (float*)d_out;

  char* ws = (char*)d_ws;
  float* feat = (float*)ws;                                  // 4096*288 f32
  float4* keypts = (float4*)(ws + (size_t)(B_ * K_) * CIN * sizeof(float));
  float4* sorted = (float4*)(ws + (size_t)(B_ * K_) * CIN * sizeof(float)
                                + (size_t)(B_ * K_) * sizeof(float4));

  hipLaunchKernelGGL(sort_kernel, dim3(B_), dim3(1024), 0, stream, points, sorted);
  hipLaunchKernelGGL(fps_kernel, dim3(B_), dim3(FPS_T), 0, stream,
                     points, sorted, keypts);
  hipLaunchKernelGGL(bilinear_kernel, dim3(B_ * K_), dim3(256), 0, stream,
                     bev, keypts, feat);
  hipLaunchKernelGGL(group_kernel, dim3(B_ * K_ / 4), dim3(256), 0, stream,
                     points, keypts, sa_w1, sa_s1, sa_b1, sa_w2, sa_s2, sa_b2, feat);
  hipLaunchKernelGGL(fuse_kernel, dim3(B_ * K_ / 8), dim3(128), 0, stream,
                     feat, fuse_w, fuse_s, fuse_b, out);
}

// Round 17
// 2323.260 us; speedup vs baseline: 1.4644x; 1.4644x over previous
//
#include <hip/hip_runtime.h>

#define B_ 2
#define N_ 16384
#define K_ 2048
#define CBEV 256
#define HH 128
#define WW 128
#define CIN 288
#define COUT 128

typedef float f32x2 __attribute__((ext_vector_type(2)));
typedef float f32x4 __attribute__((ext_vector_type(4)));

// DPP max step: cross-lane move at VALU latency; bound_ctrl=1 fills invalid
// lanes with 0 -- safe identity since all reduced values are >= 0.
template <int CTRL>
__device__ __forceinline__ float dpp_max(float v) {
  int x = __builtin_amdgcn_update_dpp(0, __float_as_int(v), CTRL, 0xf, 0xf, true);
  return fmaxf(v, __int_as_float(x));
}

// ---------------- spatial sort (band-serpentine 32x32 over x,y) ----------------
// Continuous curve: any run of consecutive cells is spatially compact, so
// every wave gets a small bbox (no Morton discontinuities).
__global__ __launch_bounds__(1024) void sort_kernel(
    const float4* __restrict__ points, float4* __restrict__ sorted)
{
  const int b = blockIdx.x, t = threadIdx.x, lane = t & 63, wid = t >> 6;
  const float4* pts = points + (size_t)b * N_;
  float4* dst = sorted + (size_t)b * N_;
  __shared__ int hist[1024];
  __shared__ int wsum[16];
  hist[t] = 0;
  __syncthreads();
  int cells[16];
#pragma unroll
  for (int j = 0; j < 16; ++j) {
    float4 p = pts[t * 16 + j];
    int cx = min(max((int)((p.x + 51.2f) * 0.3125f), 0), 31);
    int cy = min(max((int)((p.y + 51.2f) * 0.3125f), 0), 31);
    int band = cy >> 2;                       // 0..7 (4 rows each)
    int rib = cy & 3;                         // row in band
    int col = (band & 1) ? (31 - cx) : cx;    // serpentine join at band ends
    int c = band * 128 + col * 4 + rib;       // 0..1023, continuous curve
    cells[j] = c;
    atomicAdd(&hist[c], 1);
  }
  __syncthreads();
  int own = hist[t];
  int v = own;
#pragma unroll
  for (int off = 1; off < 64; off <<= 1) {
    int n = __shfl_up(v, off);
    if (lane >= off) v += n;
  }
  if (lane == 63) wsum[wid] = v;
  __syncthreads();
  int base = 0;
  for (int i = 0; i < wid; ++i) base += wsum[i];
  int excl = base + v - own;
  __syncthreads();
  hist[t] = excl;
  __syncthreads();
#pragma unroll
  for (int j = 0; j < 16; ++j) {
    float4 p = pts[t * 16 + j];
    int pos = atomicAdd(&hist[cells[j]], 1);
    dst[pos] = p;
  }
}

// ---------------- FPS: 16 waves, wave-level bbox prune, LDS keypoint buffer ----
// Empirical optimum of this structure (R10/R16: 8 waves regress to ~3.4ms;
// R11-R15: structural variants all land 2200+-100us). Floor is the serial
// K=2048 x ~2700cyc selection chain, split ~equally between per-SIMD issue
// of the 16-wave skeleton and the dense->reduce->barrier latency chain.
#define FPS_T 1024
#define FPS_PPT 16
#define FPS_PAIRS 8
#define REG_PAIRS 4  // pairs 0..3 x,y in VGPRs; pairs 4..7 in LDS f32x4

__global__ __launch_bounds__(FPS_T)
__attribute__((amdgpu_waves_per_eu(4, 4))) void fps_kernel(
    const float4* __restrict__ points, const float4* __restrict__ sorted,
    float4* __restrict__ keypts)
{
  const int b = blockIdx.x, t = threadIdx.x, lane = t & 63, wid = t >> 6;
  const float4* sp = sorted + (size_t)b * N_;

  __shared__ f32x4 xyq[FPS_PAIRS - REG_PAIRS][FPS_T];  // 64KB (x0,x1,y0,y1)
  __shared__ float4 scoord[2][16];                     // (x,y,z,val) per wave
  __shared__ float4 kpbuf[K_];                         // 32KB: keypoint buffer

  const int base = t * FPS_PPT;

  f32x2 rx[REG_PAIRS], ry[REG_PAIRS];  // 16 VGPRs, statically indexed
  f32x2 zz[FPS_PAIRS], dd[FPS_PAIRS];
  float bxmin = 1e30f, bxmax = -1e30f, bymin = 1e30f, bymax = -1e30f;
  float bzmin = 1e30f, bzmax = -1e30f;
#pragma unroll
  for (int j = 0; j < FPS_PAIRS; ++j) {
    float4 p0 = sp[base + 2 * j];
    float4 p1 = sp[base + 2 * j + 1];
    if (j < REG_PAIRS) {
      rx[j].x = p0.x; rx[j].y = p1.x;
      ry[j].x = p0.y; ry[j].y = p1.y;
    } else {
      f32x4 v4; v4.x = p0.x; v4.y = p1.x; v4.z = p0.y; v4.w = p1.y;
      xyq[j - REG_PAIRS][t] = v4;
    }
    zz[j].x = p0.z; zz[j].y = p1.z;
    dd[j].x = 1e10f; dd[j].y = 1e10f;
    bxmin = fminf(bxmin, fminf(p0.x, p1.x)); bxmax = fmaxf(bxmax, fmaxf(p0.x, p1.x));
    bymin = fminf(bymin, fminf(p0.y, p1.y)); bymax = fmaxf(bymax, fmaxf(p0.y, p1.y));
    bzmin = fminf(bzmin, fminf(p0.z, p1.z)); bzmax = fmaxf(bzmax, fmaxf(p0.z, p1.z));
  }
  // WAVE-level bbox: one skip decision per wave
#pragma unroll
  for (int off = 1; off < 64; off <<= 1) {
    bxmin = fminf(bxmin, __shfl_xor(bxmin, off));
    bxmax = fmaxf(bxmax, __shfl_xor(bxmax, off));
    bymin = fminf(bymin, __shfl_xor(bymin, off));
    bymax = fmaxf(bymax, __shfl_xor(bymax, off));
    bzmin = fminf(bzmin, __shfl_xor(bzmin, off));
    bzmax = fmaxf(bzmax, __shfl_xor(bzmax, off));
  }
  float wtmax = 1e10f;  // this wave's exact max dd (== published wv)

  float4 q = points[(size_t)b * N_];  // seed = original index 0
  if (t == 0) kpbuf[0] = make_float4(q.x, q.y, q.z, q.w);

  for (int it = 1; it < K_; ++it) {
    const int pr = it & 1;
    // conservative lower bound of dist^2 from q to the WAVE bbox (uniform)
    float dxl = fmaxf(fmaxf(bxmin - q.x, q.x - bxmax), 0.f);
    float dyl = fmaxf(fmaxf(bymin - q.y, q.y - bymax), 0.f);
    float dzl = fmaxf(fmaxf(bzmin - q.z, q.z - bzmax), 0.f);
    float lb = dxl * dxl + dyl * dyl + dzl * dzl;
    // margin covers <=9ulp RN error; lb>=wtmax>=dd[j] forall j -> exact no-op
    if (lb * 0.999999f < wtmax) {
#pragma clang fp contract(off)
      f32x2 qx, qy, qz;
      qx.x = q.x; qx.y = q.x;
      qy.x = q.y; qy.y = q.y;
      qz.x = q.z; qz.y = q.z;
      f32x2 rm; rm.x = -1.f; rm.y = -1.f;
      // reg-resident pairs: pure VALU
#pragma unroll
      for (int j = 0; j < REG_PAIRS; ++j) {
        // EXACT reference arithmetic: RN sub/mul/add, ((dx^2+dy^2)+dz^2)
        f32x2 dx = rx[j] - qx;
        f32x2 dy = ry[j] - qy;
        f32x2 dz = zz[j] - qz;
        f32x2 d = dx * dx + dy * dy + dz * dz;
        d = __builtin_elementwise_min(dd[j], d);
        dd[j] = d;
        rm = __builtin_elementwise_max(rm, d);
      }
      // LDS pairs: one ds_read_b128 each
#pragma unroll
      for (int j = REG_PAIRS; j < FPS_PAIRS; ++j) {
        f32x4 v4 = xyq[j - REG_PAIRS][t];
        f32x2 x; x.x = v4.x; x.y = v4.y;
        f32x2 y; y.x = v4.z; y.y = v4.w;
        f32x2 dx = x - qx;
        f32x2 dy = y - qy;
        f32x2 dz = zz[j] - qz;
        f32x2 d = dx * dx + dy * dy + dz * dz;
        d = __builtin_elementwise_min(dd[j], d);
        dd[j] = d;
        rm = __builtin_elementwise_max(rm, d);
      }
      float tmax = fmaxf(rm.x, rm.y);
      // wave max via DPP
      float wred = tmax;
      wred = dpp_max<0x111>(wred);  // row_shr:1
      wred = dpp_max<0x112>(wred);  // row_shr:2
      wred = dpp_max<0x114>(wred);  // row_shr:4
      wred = dpp_max<0x118>(wred);  // row_shr:8
      wred = dpp_max<0x142>(wred);  // row_bcast:15
      wred = dpp_max<0x143>(wred);  // row_bcast:31
      float wv = __int_as_float(
          __builtin_amdgcn_readlane(__float_as_int(wred), 63));
      wtmax = wv;  // stays exact while pruned (dd unchanged then)
      // winner lane = lowest tied lane (lanes are sorted-index-ordered)
      unsigned long long mb = __ballot(tmax == wv);
      int src = __ffsll((long long)mb) - 1;
      if (lane == src) {
        // rescan own dd; reverse order + x-after-y -> smallest offset wins
        int tjoff = 0;
#pragma unroll
        for (int jj = FPS_PAIRS - 1; jj >= 0; --jj) {
          if (dd[jj].y == wv) tjoff = 2 * jj + 1;
          if (dd[jj].x == wv) tjoff = 2 * jj;
        }
        float xx = 0.f, yy = 0.f;
#pragma unroll
        for (int jj = 0; jj < REG_PAIRS; ++jj) {  // static indexing only
          xx = (tjoff == 2 * jj) ? rx[jj].x : xx;
          xx = (tjoff == 2 * jj + 1) ? rx[jj].y : xx;
          yy = (tjoff == 2 * jj) ? ry[jj].x : yy;
          yy = (tjoff == 2 * jj + 1) ? ry[jj].y : yy;
        }
        if (tjoff >= 2 * REG_PAIRS) {  // dynamic LDS fetch is fine
          const float* lp = (const float*)&xyq[(tjoff >> 1) - REG_PAIRS][t];
          int sub = tjoff & 1;
          xx = lp[sub];
          yy = lp[2 + sub];
        }
        float zs = 0.f;
#pragma unroll
        for (int jj = 0; jj < FPS_PAIRS; ++jj) {
          zs = (tjoff == 2 * jj) ? zz[jj].x : zs;
          zs = (tjoff == 2 * jj + 1) ? zz[jj].y : zs;
        }
        scoord[pr][wid] = make_float4(xx, yy, zs, wv);
      }
    } else {
      // pruned wave: winner unchanged; copy last slot to this parity
      if (lane == 0) scoord[pr][wid] = scoord[pr ^ 1][wid];
    }
    __syncthreads();  // single barrier; parity double-buffer avoids WAR
    // global winner among 16 slots: one b128 read + DPP + readlane bcast
    float4 f4 = scoord[pr][lane & 15];
    float v = f4.w;
    float g = v;
    g = dpp_max<0x111>(g);
    g = dpp_max<0x112>(g);
    g = dpp_max<0x114>(g);
    g = dpp_max<0x118>(g);
    float gm = __int_as_float(
        __builtin_amdgcn_readlane(__float_as_int(g), 15));
    unsigned long long mb2 = __ballot(v == gm);
    int sww = (__ffsll((long long)mb2) - 1) & 15;  // uniform (from SGPR mask)
    q.x = __int_as_float(__builtin_amdgcn_readlane(__float_as_int(f4.x), sww));
    q.y = __int_as_float(__builtin_amdgcn_readlane(__float_as_int(f4.y), sww));
    q.z = __int_as_float(__builtin_amdgcn_readlane(__float_as_int(f4.z), sww));
    if (t == 0) kpbuf[it] = make_float4(q.x, q.y, q.z, 0.f);  // LDS only
  }
  __syncthreads();
  // single coalesced burst of all keypoints at the end
  for (int i = t; i < K_; i += FPS_T)
    keypts[(size_t)b * K_ + i] = kpbuf[i];
}

// ---------------- bilinear BEV sampling ----------------
__global__ __launch_bounds__(256) void bilinear_kernel(
    const float* __restrict__ bev, const float4* __restrict__ keypts,
    float* __restrict__ feat)
{
  const int kb = blockIdx.x;      // 0..B*K-1
  const int b = kb >> 11;         // / K_
  const int c = threadIdx.x;      // channel
  float4 kp = keypts[kb];
  // exact reference op order: (x - (-51.2)) / 0.1 / 8.0 in f32 RN
  float x = __fsub_rn(kp.x, -51.2f); x = x / 0.1f; x = x / 8.0f;
  float y = __fsub_rn(kp.y, -51.2f); y = y / 0.1f; y = y / 8.0f;
  int xf = (int)floorf(x);
  int yf = (int)floorf(y);
  int x0 = min(max(xf, 0), WW - 1);
  int x1 = min(max(xf + 1, 0), WW - 1);
  int y0 = min(max(yf, 0), HH - 1);
  int y1 = min(max(yf + 1, 0), HH - 1);
  float x0f = (float)x0, x1f = (float)x1, y0f = (float)y0, y1f = (float)y1;
  float wa = (x1f - x) * (y1f - y);
  float wb = (x1f - x) * (y - y0f);
  float wc = (x - x0f) * (y1f - y);
  float wd = (x - x0f) * (y - y0f);
  const float* bb = bev + ((size_t)b * CBEV + c) * (HH * WW);
  float Ia = bb[y0 * WW + x0];
  float Ib = bb[y1 * WW + x0];
  float Ic = bb[y0 * WW + x1];
  float Id = bb[y1 * WW + x1];
  float v = Ia * wa + Ib * wb + Ic * wc + Id * wd;
  feat[(size_t)kb * CIN + c] = v;
}

// ---------------- grouping + 2x tiny MLP + maxpool ----------------
__global__ __launch_bounds__(256) void group_kernel(
    const float4* __restrict__ points, const float4* __restrict__ keypts,
    const float* __restrict__ sa_w1, const float* __restrict__ sa_s1,
    const float* __restrict__ sa_b1, const float* __restrict__ sa_w2,
    const float* __restrict__ sa_s2, const float* __restrict__ sa_b2,
    float* __restrict__ feat)
{
  const int w = threadIdx.x >> 6;      // wave id 0..3
  const int lane = threadIdx.x & 63;
  const int kb = blockIdx.x * 4 + w;   // keypoint id
  const int b = kb >> 11;
  const int d = lane & 15;
  __shared__ int l1[4][16];
  __shared__ int l2[4][32];
  const float4* pts = points + (size_t)b * N_;
  float4 kp = keypts[kb];
  const float r2a = (float)(0.4 * 0.4);
  const float r2b = (float)(0.8 * 0.8);
  int c1 = 0, c2 = 0;
  for (int base = 0; base < N_; base += 64) {
    float4 p = pts[base + lane];
    float dx = __fsub_rn(kp.x, p.x);
    float dy = __fsub_rn(kp.y, p.y);
    float dz = __fsub_rn(kp.z, p.z);
    float d2 = __fadd_rn(__fadd_rn(__fmul_rn(dx, dx), __fmul_rn(dy, dy)),
                         __fmul_rn(dz, dz));
    unsigned long long m2 = __ballot(d2 < r2b);
    unsigned long long m1 = __ballot(d2 < r2a);
    unsigned long long below = (lane == 0) ? 0ull : ((~0ull) >> (64 - lane));
    if (c2 < 32 && m2) {
      int pos = c2 + __popcll(m2 & below);
      if (((m2 >> lane) & 1ull) && pos < 32) l2[w][pos] = base + lane;
      c2 += __popcll(m2); if (c2 > 32) c2 = 32;
    }
    if (c1 < 16 && m1) {
      int pos = c1 + __popcll(m1 & below);
      if (((m1 >> lane) & 1ull) && pos < 16) l1[w][pos] = base + lane;
      c1 += __popcll(m1); if (c1 > 16) c1 = 16;
    }
    if (c1 >= 16 && c2 >= 32) break;
  }
  __syncthreads();

  float pooled[2];
#pragma unroll
  for (int br = 0; br < 2; ++br) {
    const int wo1 = br * 64, so1 = br * 16, wo2 = br * 256;
    float w1r[4], w2r[16];
#pragma unroll
    for (int c = 0; c < 4; ++c) w1r[c] = sa_w1[wo1 + c * 16 + d];
#pragma unroll
    for (int c = 0; c < 16; ++c) w2r[c] = sa_w2[wo2 + c * 16 + d];
    float s1d = sa_s1[so1 + d], b1d = sa_b1[so1 + d];
    float s2d = sa_s2[so1 + d], b2d = sa_b2[so1 + d];
    int cnt = (br == 0) ? c1 : c2;
    float vm = -1e30f;
    int n = cnt > 0 ? cnt : 1;
    for (int j = 0; j < n; ++j) {
      float g0 = 0.f, g1 = 0.f, g2 = 0.f, g3 = 0.f;
      if (j < cnt) {
        int pi = (br == 0) ? l1[w][j] : l2[w][j];
        float4 p = pts[pi];
        g0 = p.x - kp.x; g1 = p.y - kp.y; g2 = p.z - kp.z; g3 = p.w;
      }
      float a = g0 * w1r[0] + g1 * w1r[1] + g2 * w1r[2] + g3 * w1r[3];
      float h1 = fmaxf(0.f, fmaf(a, s1d, b1d));
      float a2 = 0.f;
#pragma unroll
      for (int c = 0; c < 16; ++c) a2 = fmaf(__shfl(h1, c), w2r[c], a2);
      float h2 = fmaxf(0.f, fmaf(a2, s2d, b2d));
      vm = fmaxf(vm, h2);
    }
    pooled[br] = vm;
  }
  if (lane < 16) {
    feat[(size_t)kb * CIN + 256 + d] = pooled[0];
    feat[(size_t)kb * CIN + 272 + d] = pooled[1];
  }
}

// ---------------- fused linear + relu ----------------
__global__ __launch_bounds__(128) void fuse_kernel(
    const float* __restrict__ feat, const float* __restrict__ fw,
    const float* __restrict__ fs, const float* __restrict__ fb,
    float* __restrict__ out)
{
  __shared__ float rows[8 * CIN];
  const int d = threadIdx.x;
  const size_t r0 = (size_t)blockIdx.x * 8;
  for (int i = d; i < 8 * CIN; i += 128) rows[i] = feat[r0 * CIN + i];
  __syncthreads();
  float acc[8];
#pragma unroll
  for (int r = 0; r < 8; ++r) acc[r] = 0.f;
  for (int c = 0; c < CIN; ++c) {
    float wv = fw[c * COUT + d];
#pragma unroll
    for (int r = 0; r < 8; ++r) acc[r] = fmaf(rows[r * CIN + c], wv, acc[r]);
  }
  float sd = fs[d], bd = fb[d];
#pragma unroll
  for (int r = 0; r < 8; ++r)
    out[(r0 + r) * COUT + d] = fmaxf(0.f, fmaf(acc[r], sd, bd));
}

extern "C" void kernel_launch(void* const* d_in, const int* in_sizes, int n_in,
                              void* d_out, int out_size, void* d_ws, size_t ws_size,
                              hipStream_t stream) {
  const float4* points = (const float4*)d_in[0];
  const float* bev    = (const float*)d_in[1];
  const float* sa_w1  = (const float*)d_in[2];
  const float* sa_s1  = (const float*)d_in[3];
  const float* sa_b1  = (const float*)d_in[4];
  const float* sa_w2  = (const float*)d_in[5];
  const float* sa_s2  = (const float*)d_in[6];
  const float* sa_b2  = (const float*)d_in[7];
  const float* fuse_w = (const float*)d_in[8];
  const float* fuse_s = (const float*)d_in[9];
  const float* fuse_b = (const float*)d_in[10];
  float* out = (float*)d_out;

  char* ws = (char*)d_ws;
  float* feat = (float*)ws;                                  // 4096*288 f32
  float4* keypts = (float4*)(ws + (size_t)(B_ * K_) * CIN * sizeof(float));
  float4* sorted = (float4*)(ws + (size_t)(B_ * K_) * CIN * sizeof(float)
                                + (size_t)(B_ * K_) * sizeof(float4));

  hipLaunchKernelGGL(sort_kernel, dim3(B_), dim3(1024), 0, stream, points, sorted);
  hipLaunchKernelGGL(fps_kernel, dim3(B_), dim3(FPS_T), 0, stream,
                     points, sorted, keypts);
  hipLaunchKernelGGL(bilinear_kernel, dim3(B_ * K_), dim3(256), 0, stream,
                     bev, keypts, feat);
  hipLaunchKernelGGL(group_kernel, dim3(B_ * K_ / 4), dim3(256), 0, stream,
                     points, keypts, sa_w1, sa_s1, sa_b1, sa_w2, sa_s2, sa_b2, feat);
  hipLaunchKernelGGL(fuse_kernel, dim3(B_ * K_ / 8), dim3(128), 0, stream,
                     feat, fuse_w, fuse_s, fuse_b, out);
}